// Round 1
// baseline (1281.513 us; speedup 1.0000x reference)
//
#include <hip/hip_runtime.h>
#include <math.h>

#define F_DIM 128

// ---------------------------------------------------------------------------
// Kernel 1: segment boundaries from sorted batch_idx.
// seg[g] = first row with bidx >= g ; seg[G] = n. Covers empty graphs.
// d_ws is re-poisoned (0xAA) before every call -> must write ALL G+1 entries.
// ---------------------------------------------------------------------------
__global__ void seg_bounds_kernel(const int* __restrict__ bidx,
                                  int* __restrict__ seg, int n, int G) {
    int i = blockIdx.x * blockDim.x + threadIdx.x;
    if (i >= n) return;
    int cur = bidx[i];
    if (i == 0) {
        for (int g = 0; g <= cur; ++g) seg[g] = 0;
    } else {
        int prev = bidx[i - 1];
        for (int g = prev + 1; g <= cur; ++g) seg[g] = i;
    }
    if (i == n - 1) {
        for (int g = cur + 1; g <= G; ++g) seg[g] = n;
    }
}

// ---------------------------------------------------------------------------
// Kernel 2: ONE WAVE PER GRAPH, barrier-free online softmax-pool.
//
// Lane layout within the wave (64 lanes):
//   half = lane>>5  : 0 -> even rows of the segment, 1 -> odd rows
//   fq   = lane&31  : feature quad, features 4*fq .. 4*fq+3 (float4)
// One global_load_dwordx4 per lane covers 2 rows x 128 feats = 1024
// contiguous bytes per wave -> perfectly coalesced.
//
// Each 32-lane half runs an INDEPENDENT online softmax over its row stream
// (d is uniform within a half after the 5-step shfl_xor reduce), so the main
// loop has no cross-half communication, no LDS, no __syncthreads. The two
// halves' (m, l, acc) states merge once at the end via shfl_xor(.,32).
//
// m starts at -1e30f (finite): rescale exp(m-mn) and tail-row handling
// (d=-inf -> e=0) stay NaN-free even for empty graphs / odd-length tails.
// ---------------------------------------------------------------------------
__global__ __launch_bounds__(256)
void wave_attn_pool_kernel(const float* __restrict__ x,
                           const float* __restrict__ attn_w,
                           const int*   __restrict__ seg,
                           float* __restrict__ out,
                           int num_graphs) {
    const int tid  = threadIdx.x;
    const int lane = tid & 63;
    const int g    = (blockIdx.x * blockDim.x + tid) >> 6;   // one wave per graph
    if (g >= num_graphs) return;

    const int half = lane >> 5;      // 0: even rows, 1: odd rows
    const int fq   = lane & 31;      // float4 slot within the 128-feature row

    const int start = seg[g];
    const int end   = seg[g + 1];

    const float4  w4 = ((const float4*)attn_w)[fq];
    const float4* xp = (const float4*)x;

    float  m = -1e30f;               // finite sentinel: no -inf - -inf NaN
    float  l = 0.f;
    float4 acc = make_float4(0.f, 0.f, 0.f, 0.f);

    int base = start;

    // ---- main loop: 8 rows (4 x dwordx4 per lane) per iteration, no guards ----
    for (; base + 8 <= end; base += 8) {
        float4 v[4];
        #pragma unroll
        for (int u = 0; u < 4; ++u)
            v[u] = xp[(size_t)(base + 2 * u + half) * (F_DIM / 4) + fq];

        #pragma unroll
        for (int u = 0; u < 4; ++u) {
            float d = v[u].x * w4.x + v[u].y * w4.y + v[u].z * w4.z + v[u].w * w4.w;
            d += __shfl_xor(d, 1);
            d += __shfl_xor(d, 2);
            d += __shfl_xor(d, 4);
            d += __shfl_xor(d, 8);
            d += __shfl_xor(d, 16);          // d uniform within each 32-lane half
            const float mn = fmaxf(m, d);
            const float s  = __expf(m - mn); // ==1 when max unchanged
            const float e  = __expf(d - mn);
            m = mn;
            l = l * s + e;
            acc.x = acc.x * s + e * v[u].x;
            acc.y = acc.y * s + e * v[u].y;
            acc.z = acc.z * s + e * v[u].z;
            acc.w = acc.w * s + e * v[u].w;
        }
    }

    // ---- tail: up to 7 rows, branchless validity (uniform per half) ----
    for (; base < end; base += 2) {
        const int  row   = base + half;
        const bool valid = row < end;
        float4 v = make_float4(0.f, 0.f, 0.f, 0.f);
        if (valid) v = xp[(size_t)row * (F_DIM / 4) + fq];
        float d = v.x * w4.x + v.y * w4.y + v.z * w4.z + v.w * w4.w;
        d += __shfl_xor(d, 1);
        d += __shfl_xor(d, 2);
        d += __shfl_xor(d, 4);
        d += __shfl_xor(d, 8);
        d += __shfl_xor(d, 16);
        if (!valid) d = -INFINITY;           // e -> 0, state untouched
        const float mn = fmaxf(m, d);
        const float s  = __expf(m - mn);
        const float e  = __expf(d - mn);     // exp(-inf - finite) = 0
        m = mn;
        l = l * s + e;
        acc.x = acc.x * s + e * v.x;
        acc.y = acc.y * s + e * v.y;
        acc.z = acc.z * s + e * v.z;
        acc.w = acc.w * s + e * v.w;
    }

    // ---- merge the two halves' online states (single cross-half exchange) ----
    const float mo = __shfl_xor(m, 32);
    const float mt = fmaxf(m, mo);
    const float sc = __expf(m - mt);         // m==-1e30 both halves -> exp(0)=1, l=0
    l     *= sc;
    acc.x *= sc; acc.y *= sc; acc.z *= sc; acc.w *= sc;
    l     += __shfl_xor(l, 32);
    acc.x += __shfl_xor(acc.x, 32);
    acc.y += __shfl_xor(acc.y, 32);
    acc.z += __shfl_xor(acc.z, 32);
    acc.w += __shfl_xor(acc.w, 32);

    const float inv = 1.f / (l + 1e-16f);    // empty graph -> acc=0 -> out=0
    if (half == 0) {
        float4 o = make_float4(acc.x * inv, acc.y * inv, acc.z * inv, acc.w * inv);
        ((float4*)out)[(size_t)g * (F_DIM / 4) + fq] = o;
    }
}

extern "C" void kernel_launch(void* const* d_in, const int* in_sizes, int n_in,
                              void* d_out, int out_size, void* d_ws, size_t ws_size,
                              hipStream_t stream) {
    const float* x      = (const float*)d_in[0];
    const float* attn_w = (const float*)d_in[1];
    // d_in[2] = attn_b: cancels inside the segment softmax -> unused.
    const int*   bidx   = (const int*)d_in[3];

    const int n_total    = in_sizes[0] / F_DIM;
    const int num_graphs = out_size / F_DIM;

    int* seg = (int*)d_ws;   // G+1 ints

    seg_bounds_kernel<<<(n_total + 255) / 256, 256, 0, stream>>>(
        bidx, seg, n_total, num_graphs);

    // one wave (64 lanes) per graph, 4 waves per 256-thread block
    const int blocks = (num_graphs + 3) / 4;
    wave_attn_pool_kernel<<<blocks, 256, 0, stream>>>(
        x, attn_w, seg, (float*)d_out, num_graphs);
}